// Round 1
// baseline (449.143 us; speedup 1.0000x reference)
//
#include <hip/hip_runtime.h>
#include <stdint.h>
#include <stddef.h>
#include <algorithm>

// GraphSAGE 2-layer, MI355X. Reference RNG: JAX threefry, partitionable=True
// (modern default). Perms computed host-side each call (deterministic).

#define D       256
#define BATCH   1024
#define F1      25
#define F2      10
#define MAXDEG  128
#define OUTD    128

struct Perms { int p1[F1]; int p2[F2]; };

// ---------------- host-side threefry2x32 (JAX-exact) ----------------
static inline uint32_t rotl32(uint32_t x, int d){ return (x<<d)|(x>>(32-d)); }

static void tf2x32(uint32_t k0, uint32_t k1, uint32_t x0, uint32_t x1,
                   uint32_t* o0, uint32_t* o1){
  uint32_t ks0=k0, ks1=k1, ks2 = k0^k1^0x1BD11BDAu;
  static const int rot[2][4] = {{13,15,26,6},{17,29,16,24}};
  x0 += ks0; x1 += ks1;
  for (int g=0; g<5; ++g){
    const int* r = rot[g&1];
    for (int i=0;i<4;++i){ x0 += x1; x1 = rotl32(x1, r[i]) ^ x0; }
    switch(g){
      case 0: x0 += ks1; x1 += ks2 + 1u; break;
      case 1: x0 += ks2; x1 += ks0 + 2u; break;
      case 2: x0 += ks0; x1 += ks1 + 3u; break;
      case 3: x0 += ks1; x1 += ks2 + 4u; break;
      default:x0 += ks2; x1 += ks0 + 5u; break;
    }
  }
  *o0 = x0; *o1 = x1;
}

// permutation(key, 128) with threefry_partitionable=True semantics:
//   key, subkey = split(key)        -> subkey = threefry(key, (0,1)) [both words]
//   bits[i] = y0^y1 of threefry(subkey, (0,i))   (32-bit random_bits)
//   perm = stable argsort(bits)     (1 round for n=128)
static void mkperm(uint32_t ka, uint32_t kb, int n, int* outp){
  uint32_t ska, skb;
  tf2x32(ka, kb, 0u, 1u, &ska, &skb);
  uint32_t bits[MAXDEG];
  int idxs[MAXDEG];
  for (int i=0;i<MAXDEG;++i){
    uint32_t y0,y1; tf2x32(ska,skb, 0u,(uint32_t)i, &y0,&y1);
    bits[i] = y0 ^ y1;
    idxs[i] = i;
  }
  std::stable_sort(idxs, idxs+MAXDEG,
                   [&](int a,int b){ return bits[a] < bits[b]; });
  for (int j=0;j<n;++j) outp[j] = idxs[j];
}

static void compute_perms(Perms& P){
  // key(42) data = (0,42); fold-like split: k_i = threefry(key, (0,i))
  uint32_t k1a,k1b,k2a,k2b;
  tf2x32(0u,42u, 0u,0u, &k1a,&k1b);
  tf2x32(0u,42u, 0u,1u, &k2a,&k2b);
  mkperm(k1a,k1b, F1, P.p1);
  mkperm(k2a,k2b, F2, P.p2);
}

// ---------------- device kernels ----------------

__global__ __launch_bounds__(256) void sample1_k(
    const int* __restrict__ ids, const int* __restrict__ adj,
    int* __restrict__ out, Perms P){
  int t = blockIdx.x*256 + threadIdx.x;
  if (t < BATCH*F1){
    int i = t / F1, j = t - i*F1;
    out[t] = adj[(size_t)ids[i]*MAXDEG + P.p1[j]];
  }
}

__global__ __launch_bounds__(256) void sample2_k(
    const int* __restrict__ ids1, const int* __restrict__ adj,
    int* __restrict__ out, Perms P){
  int t = blockIdx.x*256 + threadIdx.x;
  if (t < BATCH*F1*F2){
    int i = t / F2, j = t - i*F2;
    out[t] = adj[(size_t)ids1[i]*MAXDEG + P.p2[j]];
  }
}

// dst[r][d] = mean_j src[row(r,j)][d]; row = idx ? idx[r*n+j] : r*n+j
__global__ __launch_bounds__(256) void mean_rows(
    const float* __restrict__ src, const int* __restrict__ idx,
    float* __restrict__ dst, int n, float invn){
  int r = blockIdx.x, d = threadIdx.x;
  float s = 0.f;
  int base = r*n;
  for (int j=0;j<n;++j){
    int row = idx ? idx[base+j] : (base+j);
    s += src[(size_t)row*D + d];
  }
  dst[(size_t)r*D + d] = s*invn;
}

// C[r][col_off + o] = act( dot(Arow(r), W[o]) + bias[o] ), o in [0,128)
// Arow(r) = A + (rowidx?rowidx[r]:r)*256. K=256 fixed. fp32 vector GEMM.
#define BM 64
#define BN 128
#define BK 32

__global__ __launch_bounds__(256) void gemm_g(
    const float* __restrict__ A, const int* __restrict__ rowidx,
    const float* __restrict__ W, const float* __restrict__ bias,
    float* __restrict__ C, int col_off, int do_relu){
  __shared__ float As[BK][BM];   // As[k][m]
  __shared__ float Ws[BK][BN];   // Ws[k][n]
  const int tid  = threadIdx.x;
  const int row0 = blockIdx.x * BM;
  const int tr = (tid >> 4) * 4;   // 16 row-groups x 4 rows
  const int tc = (tid & 15) * 8;   // 16 col-groups x 8 cols

  // A staging: 2 float4 per thread (64 rows x 8 float4)
  int ar[2], ac4[2];
  const float* aptr[2];
  #pragma unroll
  for (int l=0;l<2;++l){
    int id = tid + l*256;
    ar[l] = id >> 3; ac4[l] = id & 7;
    int gr = row0 + ar[l];
    int sr = rowidx ? rowidx[gr] : gr;
    aptr[l] = A + (size_t)sr * D;
  }

  float acc[4][8];
  #pragma unroll
  for (int i=0;i<4;++i)
    #pragma unroll
    for (int j=0;j<8;++j) acc[i][j] = 0.f;

  for (int k0 = 0; k0 < D; k0 += BK){
    #pragma unroll
    for (int l=0;l<2;++l){
      float4 v = *(const float4*)(aptr[l] + k0 + ac4[l]*4);
      int kk = ac4[l]*4, r = ar[l];
      As[kk+0][r]=v.x; As[kk+1][r]=v.y; As[kk+2][r]=v.z; As[kk+3][r]=v.w;
    }
    #pragma unroll
    for (int l=0;l<4;++l){
      int id = tid + l*256;       // 0..1023 -> 128 rows x 8 float4
      int o = id >> 3, c4 = id & 7;
      float4 v = *(const float4*)(W + (size_t)o*D + k0 + c4*4);
      int kk = c4*4;
      Ws[kk+0][o]=v.x; Ws[kk+1][o]=v.y; Ws[kk+2][o]=v.z; Ws[kk+3][o]=v.w;
    }
    __syncthreads();
    #pragma unroll
    for (int k=0;k<BK;++k){
      float4 a4 = *(const float4*)&As[k][tr];
      float4 w0 = *(const float4*)&Ws[k][tc];
      float4 w1 = *(const float4*)&Ws[k][tc+4];
      float a[4] = {a4.x,a4.y,a4.z,a4.w};
      float wv[8] = {w0.x,w0.y,w0.z,w0.w,w1.x,w1.y,w1.z,w1.w};
      #pragma unroll
      for (int i=0;i<4;++i)
        #pragma unroll
        for (int j=0;j<8;++j) acc[i][j] += a[i]*wv[j];
    }
    __syncthreads();
  }

  float4 b0 = *(const float4*)(bias + tc);
  float4 b1 = *(const float4*)(bias + tc + 4);
  float bb[8] = {b0.x,b0.y,b0.z,b0.w,b1.x,b1.y,b1.z,b1.w};
  #pragma unroll
  for (int i=0;i<4;++i){
    size_t gr = (size_t)(row0 + tr + i);
    float o[8];
    #pragma unroll
    for (int j=0;j<8;++j){
      float v = acc[i][j] + bb[j];
      o[j] = do_relu ? fmaxf(v, 0.f) : v;
    }
    float4* dst = (float4*)(C + gr*D + col_off + tc);
    dst[0] = make_float4(o[0],o[1],o[2],o[3]);
    dst[1] = make_float4(o[4],o[5],o[6],o[7]);
  }
}

// ---------------- launch ----------------
extern "C" void kernel_launch(void* const* d_in, const int* in_sizes, int n_in,
                              void* d_out, int out_size, void* d_ws, size_t ws_size,
                              hipStream_t stream){
  const int*   ids   = (const int*)  d_in[0];
  const int*   adj   = (const int*)  d_in[1];
  const float* feats = (const float*)d_in[2];
  const float* W1x   = (const float*)d_in[3];
  const float* b1x   = (const float*)d_in[4];
  const float* W1n   = (const float*)d_in[5];
  const float* b1n   = (const float*)d_in[6];
  const float* W2x   = (const float*)d_in[7];
  const float* b2x   = (const float*)d_in[8];
  const float* W2n   = (const float*)d_in[9];
  const float* b2n   = (const float*)d_in[10];
  float* out = (float*)d_out;

  Perms P;
  compute_perms(P);

  char* w = (char*)d_ws;
  auto alloc = [&](size_t bytes)->char*{
    char* p = w; w += (bytes + 255) & ~(size_t)255; return p;
  };
  int*   ids1 = (int*)  alloc((size_t)BATCH*F1*sizeof(int));
  int*   ids2 = (int*)  alloc((size_t)BATCH*F1*F2*sizeof(int));
  float* M1   = (float*)alloc((size_t)BATCH*F1*D*sizeof(float));  // 26.2 MB
  float* z1   = (float*)alloc((size_t)BATCH*F1*D*sizeof(float));  // 26.2 MB
  float* M0   = (float*)alloc((size_t)BATCH*D*sizeof(float));
  float* z0   = (float*)alloc((size_t)BATCH*D*sizeof(float));
  float* M2   = (float*)alloc((size_t)BATCH*D*sizeof(float));

  const int M1rows = BATCH*F1;       // 25600

  hipLaunchKernelGGL(sample1_k, dim3((BATCH*F1+255)/256), dim3(256), 0, stream,
                     ids, adj, ids1, P);
  hipLaunchKernelGGL(sample2_k, dim3((BATCH*F1*F2+255)/256), dim3(256), 0, stream,
                     ids1, adj, ids2, P);

  // neighbor means (gathered)
  hipLaunchKernelGGL(mean_rows, dim3(M1rows), dim3(256), 0, stream,
                     feats, ids2, M1, F2, 1.f/F2);
  hipLaunchKernelGGL(mean_rows, dim3(BATCH), dim3(256), 0, stream,
                     feats, ids1, M0, F1, 1.f/F1);

  // layer 1 (relu): z1 = [feats[ids1] @ W1x^T + b1x | M1 @ W1n^T + b1n]
  hipLaunchKernelGGL(gemm_g, dim3(M1rows/BM), dim3(256), 0, stream,
                     feats, ids1, W1x, b1x, z1, 0, 1);
  hipLaunchKernelGGL(gemm_g, dim3(M1rows/BM), dim3(256), 0, stream,
                     M1, (const int*)nullptr, W1n, b1n, z1, OUTD, 1);
  // z0 = [feats[ids] @ W1x^T + b1x | M0 @ W1n^T + b1n]
  hipLaunchKernelGGL(gemm_g, dim3(BATCH/BM), dim3(256), 0, stream,
                     feats, ids, W1x, b1x, z0, 0, 1);
  hipLaunchKernelGGL(gemm_g, dim3(BATCH/BM), dim3(256), 0, stream,
                     M0, (const int*)nullptr, W1n, b1n, z0, OUTD, 1);

  // mean of z1 groups of 25
  hipLaunchKernelGGL(mean_rows, dim3(BATCH), dim3(256), 0, stream,
                     z1, (const int*)nullptr, M2, F1, 1.f/F1);

  // layer 2 (no act): out = [z0 @ W2x^T + b2x | M2 @ W2n^T + b2n]
  hipLaunchKernelGGL(gemm_g, dim3(BATCH/BM), dim3(256), 0, stream,
                     z0, (const int*)nullptr, W2x, b2x, out, 0, 0);
  hipLaunchKernelGGL(gemm_g, dim3(BATCH/BM), dim3(256), 0, stream,
                     M2, (const int*)nullptr, W2n, b2n, out, OUTD, 0);
}

// Round 2
// 316.194 us; speedup vs baseline: 1.4205x; 1.4205x over previous
//
#include <hip/hip_runtime.h>
#include <stdint.h>
#include <stddef.h>
#include <algorithm>

// GraphSAGE 2-layer, MI355X. RNG: JAX threefry partitionable (verified R1).
// R2: fused per-batch-element mega kernel (no z1/M0/z0 materialization),
// unrolled float4 wave-per-row M1 mean.

#define D       256
#define D4      64
#define BATCH   1024
#define F1      25
#define F2      10
#define MAXDEG  128
#define OUTD    128
#define BKW     8

struct Perms { int p1[F1]; int p2[F2]; };

// ---------------- host-side threefry2x32 (JAX-exact, verified R1) ----------
static inline uint32_t rotl32(uint32_t x, int d){ return (x<<d)|(x>>(32-d)); }

static void tf2x32(uint32_t k0, uint32_t k1, uint32_t x0, uint32_t x1,
                   uint32_t* o0, uint32_t* o1){
  uint32_t ks0=k0, ks1=k1, ks2 = k0^k1^0x1BD11BDAu;
  static const int rot[2][4] = {{13,15,26,6},{17,29,16,24}};
  x0 += ks0; x1 += ks1;
  for (int g=0; g<5; ++g){
    const int* r = rot[g&1];
    for (int i=0;i<4;++i){ x0 += x1; x1 = rotl32(x1, r[i]) ^ x0; }
    switch(g){
      case 0: x0 += ks1; x1 += ks2 + 1u; break;
      case 1: x0 += ks2; x1 += ks0 + 2u; break;
      case 2: x0 += ks0; x1 += ks1 + 3u; break;
      case 3: x0 += ks1; x1 += ks2 + 4u; break;
      default:x0 += ks2; x1 += ks0 + 5u; break;
    }
  }
  *o0 = x0; *o1 = x1;
}

static void mkperm(uint32_t ka, uint32_t kb, int n, int* outp){
  uint32_t ska, skb;
  tf2x32(ka, kb, 0u, 1u, &ska, &skb);
  uint32_t bits[MAXDEG];
  int idxs[MAXDEG];
  for (int i=0;i<MAXDEG;++i){
    uint32_t y0,y1; tf2x32(ska,skb, 0u,(uint32_t)i, &y0,&y1);
    bits[i] = y0 ^ y1;
    idxs[i] = i;
  }
  std::stable_sort(idxs, idxs+MAXDEG,
                   [&](int a,int b){ return bits[a] < bits[b]; });
  for (int j=0;j<n;++j) outp[j] = idxs[j];
}

static void compute_perms(Perms& P){
  uint32_t k1a,k1b,k2a,k2b;
  tf2x32(0u,42u, 0u,0u, &k1a,&k1b);
  tf2x32(0u,42u, 0u,1u, &k2a,&k2b);
  mkperm(k1a,k1b, F1, P.p1);
  mkperm(k2a,k2b, F2, P.p2);
}

// ---------------- device kernels ----------------

__global__ __launch_bounds__(256) void sample1_k(
    const int* __restrict__ ids, const int* __restrict__ adj,
    int* __restrict__ out, Perms P){
  int t = blockIdx.x*256 + threadIdx.x;
  if (t < BATCH*F1){
    int i = t / F1, j = t - i*F1;
    out[t] = adj[(size_t)ids[i]*MAXDEG + P.p1[j]];
  }
}

__global__ __launch_bounds__(256) void sample2_k(
    const int* __restrict__ ids1, const int* __restrict__ adj,
    int* __restrict__ out, Perms P){
  int t = blockIdx.x*256 + threadIdx.x;
  if (t < BATCH*F1*F2){
    int i = t / F2, j = t - i*F2;
    out[t] = adj[(size_t)ids1[i]*MAXDEG + P.p2[j]];
  }
}

// M1[r] = mean_{j<10} feats[ids2[r*10+j]]; one wave per output row,
// lane l owns float4 column l; 10 gathers fully unrolled -> 10 loads in
// flight per wave, each a coalesced 1KB row read.
__global__ __launch_bounds__(256) void mean10_k(
    const float4* __restrict__ feats4, const int* __restrict__ ids2,
    float4* __restrict__ M14){
  const int lane = threadIdx.x & 63;
  const int r = blockIdx.x*4 + (threadIdx.x >> 6);
  const int base = r*F2;
  float4 s = {0.f,0.f,0.f,0.f};
  #pragma unroll
  for (int j=0;j<F2;++j){
    int src = ids2[base+j];
    float4 v = feats4[(size_t)src*D4 + lane];
    s.x += v.x; s.y += v.y; s.z += v.z; s.w += v.w;
  }
  const float inv = 1.f/F2;
  s.x*=inv; s.y*=inv; s.z*=inv; s.w*=inv;
  M14[(size_t)r*D4 + lane] = s;
}

__device__ __forceinline__ float getc(const float4& v, int c){
  switch(c){ case 0: return v.x; case 1: return v.y; case 2: return v.z;
             default: return v.w; }
}

// One block per batch element b:
//  Ab rows 0..24 = feats[ids1[b,:]], row 25 = feats[ids[b]]  (LDS)
//  Mb rows 0..24 = M1[b*25..], row 25 = M0 = colmean(Ab[0:25])
//  Z = relu([Ab@W1x^T | Mb@W1n^T] + b1)  -> rows 0..24 colmean -> M2,
//  row 25 -> z0;  out[b] = [z0@W2x^T + b2x | M2@W2n^T + b2n].
__global__ __launch_bounds__(256, 2) void mega_k(
    const float4* __restrict__ feats4,
    const int* __restrict__ ids, const int* __restrict__ ids1,
    const float4* __restrict__ M14,
    const float* __restrict__ W1x, const float* __restrict__ b1x,
    const float* __restrict__ W1n, const float* __restrict__ b1n,
    const float* __restrict__ W2x, const float* __restrict__ b2x,
    const float* __restrict__ W2n, const float* __restrict__ b2n,
    float* __restrict__ out)
{
  __shared__ float Ab[32][D];       // 32 KB; reused as Z after GEMM
  __shared__ float Mb[32][D];       // 32 KB
  __shared__ float Wt[BKW][260];    // 8.3 KB, k-major W tile (both halves)
  __shared__ float M2s[D];
  __shared__ float biasz[D];
  __shared__ int   sids[32];

  const int b = blockIdx.x;
  const int tid = threadIdx.x;

  if (tid < 32) sids[tid] = (tid < F1) ? ids1[b*F1 + tid] : ids[b];
  if (tid < 64){
    float4 v = (tid < 32) ? ((const float4*)b1x)[tid]
                          : ((const float4*)b1n)[tid-32];
    ((float4*)biasz)[tid] = v;
  }
  __syncthreads();

  // stage Ab rows 0..25 (gathered), Mb rows 0..24 (contiguous), pad zeros
  for (int idx = tid; idx < 26*D4; idx += 256){
    int r = idx >> 6, c4 = idx & 63;
    float4 v = feats4[(size_t)sids[r]*D4 + c4];
    *(float4*)&Ab[r][c4*4] = v;
  }
  for (int idx = tid; idx < F1*D4; idx += 256){
    int r = idx >> 6, c4 = idx & 63;
    float4 v = M14[(size_t)(b*F1 + r)*D4 + c4];
    *(float4*)&Mb[r][c4*4] = v;
  }
  for (int idx = tid; idx < 6*D4; idx += 256){
    int r = 26 + (idx >> 6), c4 = idx & 63;
    float4 z = {0.f,0.f,0.f,0.f};
    *(float4*)&Ab[r][c4*4] = z;
    *(float4*)&Mb[r][c4*4] = z;
  }
  __syncthreads();

  // M0 -> Mb[25]
  {
    float s = 0.f;
    #pragma unroll
    for (int i=0;i<F1;++i) s += Ab[i][tid];
    Mb[25][tid] = s * (1.f/F1);
  }
  __syncthreads();

  // ---- GEMM: C[32][256], cols 0..127 = Ab@W1x^T, 128..255 = Mb@W1n^T ----
  const int oq = tid & 31;          // 32 col groups x 8 cols
  const int rq = tid >> 5;          // 8 row groups x 4 rows
  const int o0 = oq * 8;
  const bool left = (o0 < OUTD);
  const float (*Asrc)[D] = (const float (*)[D])(left ? Ab : Mb);

  float acc[4][8];
  #pragma unroll
  for (int i=0;i<4;++i)
    #pragma unroll
    for (int j=0;j<8;++j) acc[i][j] = 0.f;

  for (int kt = 0; kt < D; kt += BKW){
    // stage Wt[k][o]: rows 0..127 = W1x, 128..255 = W1n (8-k tile)
    #pragma unroll
    for (int l=0;l<2;++l){
      int id = tid + l*256;
      int o = id >> 1, kc = id & 1;
      const float* src = (o < OUTD) ? (W1x + (size_t)o*D)
                                    : (W1n + (size_t)(o-OUTD)*D);
      float4 v = *(const float4*)(src + kt + kc*4);
      Wt[kc*4+0][o] = v.x; Wt[kc*4+1][o] = v.y;
      Wt[kc*4+2][o] = v.z; Wt[kc*4+3][o] = v.w;
    }
    __syncthreads();
    #pragma unroll
    for (int k4 = 0; k4 < BKW; k4 += 4){
      float4 a[4];
      #pragma unroll
      for (int i=0;i<4;++i) a[i] = *(const float4*)&Asrc[rq*4+i][kt+k4];
      #pragma unroll
      for (int c=0;c<4;++c){
        float4 w0 = *(const float4*)&Wt[k4+c][o0];
        float4 w1 = *(const float4*)&Wt[k4+c][o0+4];
        #pragma unroll
        for (int i=0;i<4;++i){
          float av = getc(a[i], c);
          acc[i][0] += av*w0.x; acc[i][1] += av*w0.y;
          acc[i][2] += av*w0.z; acc[i][3] += av*w0.w;
          acc[i][4] += av*w1.x; acc[i][5] += av*w1.y;
          acc[i][6] += av*w1.z; acc[i][7] += av*w1.w;
        }
      }
    }
    __syncthreads();
  }

  // ---- epilogue: relu(+bias) into Ab (as Z) ----
  {
    float4 bz0 = *(const float4*)&biasz[o0];
    float4 bz1 = *(const float4*)&biasz[o0+4];
    float bb[8] = {bz0.x,bz0.y,bz0.z,bz0.w,bz1.x,bz1.y,bz1.z,bz1.w};
    #pragma unroll
    for (int i=0;i<4;++i){
      int r = rq*4 + i;
      float o[8];
      #pragma unroll
      for (int j=0;j<8;++j) o[j] = fmaxf(acc[i][j] + bb[j], 0.f);
      *(float4*)&Ab[r][o0]   = make_float4(o[0],o[1],o[2],o[3]);
      *(float4*)&Ab[r][o0+4] = make_float4(o[4],o[5],o[6],o[7]);
    }
  }
  __syncthreads();

  // M2 = colmean of Z rows 0..24
  {
    float s = 0.f;
    #pragma unroll
    for (int i=0;i<F1;++i) s += Ab[i][tid];
    M2s[tid] = s * (1.f/F1);
  }
  __syncthreads();

  // ---- layer 2: out[b][o] ----
  {
    const int o = tid;
    const bool l2l = (o < OUTD);
    const float* w2 = l2l ? (W2x + (size_t)o*D) : (W2n + (size_t)(o-OUTD)*D);
    const float* zv = l2l ? &Ab[25][0] : &M2s[0];
    float s = 0.f;
    #pragma unroll 8
    for (int k4=0;k4<D4;++k4){
      float4 wv = *(const float4*)(w2 + k4*4);
      float4 z  = *(const float4*)(zv + k4*4);
      s += wv.x*z.x + wv.y*z.y + wv.z*z.z + wv.w*z.w;
    }
    s += l2l ? b2x[o] : b2n[o-OUTD];
    out[(size_t)b*D + o] = s;
  }
}

// ---------------- launch ----------------
extern "C" void kernel_launch(void* const* d_in, const int* in_sizes, int n_in,
                              void* d_out, int out_size, void* d_ws, size_t ws_size,
                              hipStream_t stream){
  const int*   ids   = (const int*)  d_in[0];
  const int*   adj   = (const int*)  d_in[1];
  const float* feats = (const float*)d_in[2];
  const float* W1x   = (const float*)d_in[3];
  const float* b1x   = (const float*)d_in[4];
  const float* W1n   = (const float*)d_in[5];
  const float* b1n   = (const float*)d_in[6];
  const float* W2x   = (const float*)d_in[7];
  const float* b2x   = (const float*)d_in[8];
  const float* W2n   = (const float*)d_in[9];
  const float* b2n   = (const float*)d_in[10];
  float* out = (float*)d_out;

  Perms P;
  compute_perms(P);

  char* w = (char*)d_ws;
  auto alloc = [&](size_t bytes)->char*{
    char* p = w; w += (bytes + 255) & ~(size_t)255; return p;
  };
  int*   ids1 = (int*)  alloc((size_t)BATCH*F1*sizeof(int));
  int*   ids2 = (int*)  alloc((size_t)BATCH*F1*F2*sizeof(int));
  float* M1   = (float*)alloc((size_t)BATCH*F1*D*sizeof(float));  // 26.2 MB

  hipLaunchKernelGGL(sample1_k, dim3((BATCH*F1+255)/256), dim3(256), 0, stream,
                     ids, adj, ids1, P);
  hipLaunchKernelGGL(sample2_k, dim3((BATCH*F1*F2+255)/256), dim3(256), 0, stream,
                     ids1, adj, ids2, P);
  hipLaunchKernelGGL(mean10_k, dim3(BATCH*F1/4), dim3(256), 0, stream,
                     (const float4*)feats, ids2, (float4*)M1);
  hipLaunchKernelGGL(mega_k, dim3(BATCH), dim3(256), 0, stream,
                     (const float4*)feats, ids, ids1, (const float4*)M1,
                     W1x, b1x, W1n, b1n, W2x, b2x, W2n, b2n, out);
}

// Round 3
// 309.660 us; speedup vs baseline: 1.4504x; 1.0211x over previous
//
#include <hip/hip_runtime.h>
#include <stdint.h>
#include <stddef.h>
#include <algorithm>

// GraphSAGE 2-layer, MI355X. RNG: JAX threefry partitionable (verified R1).
// R3: single fully-fused kernel (sampling + neighbor means + both layers),
// conflict-free Wt mapping (stride-2-float reads), 26-row GEMM tile.

#define D       256
#define D4      64
#define BATCH   1024
#define F1      25
#define F2      10
#define MAXDEG  128
#define OUTD    128

struct Perms { int p1[F1]; int p2[F2]; };

// ---------------- host-side threefry2x32 (JAX-exact, verified R1) ----------
static inline uint32_t rotl32(uint32_t x, int d){ return (x<<d)|(x>>(32-d)); }

static void tf2x32(uint32_t k0, uint32_t k1, uint32_t x0, uint32_t x1,
                   uint32_t* o0, uint32_t* o1){
  uint32_t ks0=k0, ks1=k1, ks2 = k0^k1^0x1BD11BDAu;
  static const int rot[2][4] = {{13,15,26,6},{17,29,16,24}};
  x0 += ks0; x1 += ks1;
  for (int g=0; g<5; ++g){
    const int* r = rot[g&1];
    for (int i=0;i<4;++i){ x0 += x1; x1 = rotl32(x1, r[i]) ^ x0; }
    switch(g){
      case 0: x0 += ks1; x1 += ks2 + 1u; break;
      case 1: x0 += ks2; x1 += ks0 + 2u; break;
      case 2: x0 += ks0; x1 += ks1 + 3u; break;
      case 3: x0 += ks1; x1 += ks2 + 4u; break;
      default:x0 += ks2; x1 += ks0 + 5u; break;
    }
  }
  *o0 = x0; *o1 = x1;
}

static void mkperm(uint32_t ka, uint32_t kb, int n, int* outp){
  uint32_t ska, skb;
  tf2x32(ka, kb, 0u, 1u, &ska, &skb);
  uint32_t bits[MAXDEG];
  int idxs[MAXDEG];
  for (int i=0;i<MAXDEG;++i){
    uint32_t y0,y1; tf2x32(ska,skb, 0u,(uint32_t)i, &y0,&y1);
    bits[i] = y0 ^ y1;
    idxs[i] = i;
  }
  std::stable_sort(idxs, idxs+MAXDEG,
                   [&](int a,int b){ return bits[a] < bits[b]; });
  for (int j=0;j<n;++j) outp[j] = idxs[j];
}

static void compute_perms(Perms& P){
  uint32_t k1a,k1b,k2a,k2b;
  tf2x32(0u,42u, 0u,0u, &k1a,&k1b);
  tf2x32(0u,42u, 0u,1u, &k2a,&k2b);
  mkperm(k1a,k1b, F1, P.p1);
  mkperm(k2a,k2b, F2, P.p2);
}

// ---------------- device ----------------

__device__ __forceinline__ float getc(const float4& v, int c){
  switch(c){ case 0: return v.x; case 1: return v.y; case 2: return v.z;
             default: return v.w; }
}

// One block per batch element. Phases:
//  1. sids[0..24] = adj[ids[b], p1], sids[25] = ids[b]
//  2. nidx[250] = adj[sids[j], p2[u]];  Ab[r] = feats[sids[r]] (26 rows)
//  3. Mb[j<25] = mean_u feats[nidx[j,u]];  Mb[25] = colmean(Ab[0:25])
//  4. Z = relu([Ab@W1x^T | Mb@W1n^T] + b1) -> overwrite Ab
//  5. M2 = colmean(Z[0:25]); z0 = Z[25]
//  6. out[b] = [z0@W2x^T + b2x | M2@W2n^T + b2n]
__global__ __launch_bounds__(256, 2) void mega2_k(
    const float4* __restrict__ feats4,
    const int* __restrict__ ids, const int* __restrict__ adj,
    const float* __restrict__ W1x, const float* __restrict__ b1x,
    const float* __restrict__ W1n, const float* __restrict__ b1n,
    const float* __restrict__ W2x, const float* __restrict__ b2x,
    const float* __restrict__ W2n, const float* __restrict__ b2n,
    float* __restrict__ out, Perms P)
{
  __shared__ __attribute__((aligned(16))) float Ab[26][D];   // 26.6 KB
  __shared__ __attribute__((aligned(16))) float Mb[26][D];   // 26.6 KB
  __shared__ __attribute__((aligned(16))) float Wt[16][260]; // 16.6 KB
  __shared__ __attribute__((aligned(16))) float M2s[D];
  __shared__ int sids[26];
  __shared__ int nidx[F1*F2];

  const int b    = blockIdx.x;
  const int tid  = threadIdx.x;
  const int lane = tid & 63;
  const int wv   = tid >> 6;
  const int id   = ids[b];

  // -- phase 1: level-1 sampling --
  if (tid < F1) sids[tid] = adj[(size_t)id*MAXDEG + P.p1[tid]];
  if (tid == F1) sids[F1] = id;
  __syncthreads();

  // -- phase 2: level-2 sampling + Ab staging --
  if (tid < F1*F2){
    int j = tid / F2, u = tid - j*F2;
    nidx[tid] = adj[(size_t)sids[j]*MAXDEG + P.p2[u]];
  }
  #pragma unroll
  for (int idx = tid; idx < 26*D4; idx += 256){
    int r = idx >> 6, c = idx & 63;
    ((float4*)Ab[r])[c] = feats4[(size_t)sids[r]*D4 + c];
  }
  __syncthreads();

  // -- phase 3: neighbor means into Mb[0:25], M0 into Mb[25] --
  #pragma unroll
  for (int t = 0; t < 7; ++t){
    int j = wv + 4*t;               // wave-uniform
    if (j < F1){
      const int* np = &nidx[j*F2];
      float4 s = {0.f,0.f,0.f,0.f};
      #pragma unroll
      for (int u=0;u<F2;++u){
        float4 v = feats4[(size_t)np[u]*D4 + lane];
        s.x+=v.x; s.y+=v.y; s.z+=v.z; s.w+=v.w;
      }
      const float inv = 1.f/F2;
      s.x*=inv; s.y*=inv; s.z*=inv; s.w*=inv;
      ((float4*)Mb[j])[lane] = s;
    }
  }
  {
    float s = 0.f;
    #pragma unroll
    for (int r=0;r<F1;++r) s += Ab[r][tid];
    Mb[F1][tid] = s * (1.f/F1);
  }
  __syncthreads();

  // -- phase 4: layer-1 GEMM --
  // thread (q = tid&63, wave = row group): cols {2q,2q+1} (left, Ab@W1x)
  // and {128+2q,128+2q+1} (right, Mb@W1n); rows R0..R0+6 (clamped to 25).
  const int q  = lane;
  const int R0 = wv * 7;
  float accL[7][2], accR[7][2];
  #pragma unroll
  for (int i=0;i<7;++i){ accL[i][0]=accL[i][1]=accR[i][0]=accR[i][1]=0.f; }

  for (int kt = 0; kt < D; kt += 16){
    // stage Wt[k][o]: o<128 = W1x row o, else W1n row o-128 (16-k tile)
    #pragma unroll
    for (int l=0;l<4;++l){
      int iid = tid + l*256;            // 0..1023 -> 256 o x 4 kc
      int o = iid >> 2, kc = iid & 3;
      const float* src = (o < OUTD) ? (W1x + (size_t)o*D)
                                    : (W1n + (size_t)(o-OUTD)*D);
      float4 v = *(const float4*)(src + kt + kc*4);
      Wt[kc*4+0][o]=v.x; Wt[kc*4+1][o]=v.y;
      Wt[kc*4+2][o]=v.z; Wt[kc*4+3][o]=v.w;
    }
    __syncthreads();
    #pragma unroll
    for (int k4=0;k4<4;++k4){
      float4 aL[7], aR[7];
      #pragma unroll
      for (int i=0;i<7;++i){
        int r = R0+i; r = (r < 26) ? r : 25;   // clamp pad rows to row 25
        aL[i] = *(const float4*)&Ab[r][kt+k4*4];
        aR[i] = *(const float4*)&Mb[r][kt+k4*4];
      }
      #pragma unroll
      for (int c=0;c<4;++c){
        float2 wL = *(const float2*)&Wt[k4*4+c][2*q];
        float2 wR = *(const float2*)&Wt[k4*4+c][OUTD+2*q];
        #pragma unroll
        for (int i=0;i<7;++i){
          float a = getc(aL[i],c), m = getc(aR[i],c);
          accL[i][0] += a*wL.x; accL[i][1] += a*wL.y;
          accR[i][0] += m*wR.x; accR[i][1] += m*wR.y;
        }
      }
    }
    __syncthreads();
  }

  // -- epilogue: Z = relu(acc + bias) -> overwrite Ab --
  {
    float2 bL = *(const float2*)(b1x + 2*q);
    float2 bR = *(const float2*)(b1n + 2*q);
    #pragma unroll
    for (int i=0;i<7;++i){
      int r = R0+i;
      if (r < 26){
        float2 zL = { fmaxf(accL[i][0]+bL.x, 0.f),
                      fmaxf(accL[i][1]+bL.y, 0.f) };
        float2 zR = { fmaxf(accR[i][0]+bR.x, 0.f),
                      fmaxf(accR[i][1]+bR.y, 0.f) };
        *(float2*)&Ab[r][2*q]      = zL;
        *(float2*)&Ab[r][OUTD+2*q] = zR;
      }
    }
  }
  __syncthreads();

  // -- phase 5: M2 = colmean(Z[0:25]) --
  {
    float s = 0.f;
    #pragma unroll
    for (int r=0;r<F1;++r) s += Ab[r][tid];
    M2s[tid] = s * (1.f/F1);
  }
  __syncthreads();

  // -- phase 6: layer 2 (out cols: tid<128 from z0@W2x, else M2@W2n) --
  {
    const float* zb = (tid < OUTD) ? &Ab[F1][0] : &M2s[0];  // wave-uniform
    float acc2 = 0.f;
    for (int kt = 0; kt < D; kt += 16){
      #pragma unroll
      for (int l=0;l<4;++l){
        int iid = tid + l*256;
        int o = iid >> 2, kc = iid & 3;
        const float* src = (o < OUTD) ? (W2x + (size_t)o*D)
                                      : (W2n + (size_t)(o-OUTD)*D);
        float4 v = *(const float4*)(src + kt + kc*4);
        Wt[kc*4+0][o]=v.x; Wt[kc*4+1][o]=v.y;
        Wt[kc*4+2][o]=v.z; Wt[kc*4+3][o]=v.w;
      }
      __syncthreads();
      #pragma unroll
      for (int k=0;k<16;++k) acc2 += zb[kt+k] * Wt[k][tid];
      __syncthreads();
    }
    acc2 += (tid < OUTD) ? b2x[tid] : b2n[tid-OUTD];
    out[(size_t)b*D + tid] = acc2;
  }
}

// ---------------- launch ----------------
extern "C" void kernel_launch(void* const* d_in, const int* in_sizes, int n_in,
                              void* d_out, int out_size, void* d_ws, size_t ws_size,
                              hipStream_t stream){
  const int*   ids   = (const int*)  d_in[0];
  const int*   adj   = (const int*)  d_in[1];
  const float* feats = (const float*)d_in[2];
  const float* W1x   = (const float*)d_in[3];
  const float* b1x   = (const float*)d_in[4];
  const float* W1n   = (const float*)d_in[5];
  const float* b1n   = (const float*)d_in[6];
  const float* W2x   = (const float*)d_in[7];
  const float* b2x   = (const float*)d_in[8];
  const float* W2n   = (const float*)d_in[9];
  const float* b2n   = (const float*)d_in[10];
  float* out = (float*)d_out;

  Perms P;
  compute_perms(P);

  hipLaunchKernelGGL(mega2_k, dim3(BATCH), dim3(256), 0, stream,
                     (const float4*)feats, ids, adj,
                     W1x, b1x, W1n, b1n, W2x, b2x, W2n, b2n, out, P);
}

// Round 4
// 283.285 us; speedup vs baseline: 1.5855x; 1.0931x over previous
//
#include <hip/hip_runtime.h>
#include <stdint.h>
#include <stddef.h>
#include <algorithm>

// GraphSAGE 2-layer, MI355X. RNG: JAX threefry partitionable (verified R1).
// R4: two-kernel split — full-occupancy gather/mean kernel (bf16 M1 in ws),
// plus MFMA (bf16 16x16x32) mega kernel for layer 1 + fused layer 2.

#define D       256
#define D4      64
#define BATCH   1024
#define F1      25
#define F2      10
#define MAXDEG  128
#define OUTD    128
#define SP      264          // S pitch in bf16 elements (528 B, 2-way free)
#define ZP      260          // Z pitch in bf16 elements

struct Perms { int p1[F1]; int p2[F2]; };

// ---------------- host-side threefry2x32 (JAX-exact, verified R1) ----------
static inline uint32_t rotl32(uint32_t x, int d){ return (x<<d)|(x>>(32-d)); }

static void tf2x32(uint32_t k0, uint32_t k1, uint32_t x0, uint32_t x1,
                   uint32_t* o0, uint32_t* o1){
  uint32_t ks0=k0, ks1=k1, ks2 = k0^k1^0x1BD11BDAu;
  static const int rot[2][4] = {{13,15,26,6},{17,29,16,24}};
  x0 += ks0; x1 += ks1;
  for (int g=0; g<5; ++g){
    const int* r = rot[g&1];
    for (int i=0;i<4;++i){ x0 += x1; x1 = rotl32(x1, r[i]) ^ x0; }
    switch(g){
      case 0: x0 += ks1; x1 += ks2 + 1u; break;
      case 1: x0 += ks2; x1 += ks0 + 2u; break;
      case 2: x0 += ks0; x1 += ks1 + 3u; break;
      case 3: x0 += ks1; x1 += ks2 + 4u; break;
      default:x0 += ks2; x1 += ks0 + 5u; break;
    }
  }
  *o0 = x0; *o1 = x1;
}

static void mkperm(uint32_t ka, uint32_t kb, int n, int* outp){
  uint32_t ska, skb;
  tf2x32(ka, kb, 0u, 1u, &ska, &skb);
  uint32_t bits[MAXDEG];
  int idxs[MAXDEG];
  for (int i=0;i<MAXDEG;++i){
    uint32_t y0,y1; tf2x32(ska,skb, 0u,(uint32_t)i, &y0,&y1);
    bits[i] = y0 ^ y1;
    idxs[i] = i;
  }
  std::stable_sort(idxs, idxs+MAXDEG,
                   [&](int a,int b){ return bits[a] < bits[b]; });
  for (int j=0;j<n;++j) outp[j] = idxs[j];
}

static void compute_perms(Perms& P){
  uint32_t k1a,k1b,k2a,k2b;
  tf2x32(0u,42u, 0u,0u, &k1a,&k1b);
  tf2x32(0u,42u, 0u,1u, &k2a,&k2b);
  mkperm(k1a,k1b, F1, P.p1);
  mkperm(k2a,k2b, F2, P.p2);
}

// ---------------- device helpers ----------------
typedef short s16x8 __attribute__((ext_vector_type(8)));
typedef float f32x4 __attribute__((ext_vector_type(4)));

__device__ __forceinline__ uint16_t f2bf(float f){
  uint32_t u = __float_as_uint(f);
  u += 0x7fffu + ((u >> 16) & 1u);      // RNE
  return (uint16_t)(u >> 16);
}
__device__ __forceinline__ float bf2f(uint16_t h){
  return __uint_as_float(((uint32_t)h) << 16);
}

// ---------------- kernel A: fused sample + neighbor mean (bf16 out) -------
// wave w handles row r = blockIdx*4+w  (r = b*25+j):
//   i1 = adj[ids[b]*128 + p1[j]];  nid[u] = adj[i1*128 + p2[u]]
//   M1b[r] = bf16( mean_u feats[nid[u]] )
__global__ __launch_bounds__(256) void mean_k(
    const float4* __restrict__ feats4,
    const int* __restrict__ ids, const int* __restrict__ adj,
    uint16_t* __restrict__ M1b, Perms P)
{
  const int lane = threadIdx.x & 63;
  const int r = blockIdx.x*4 + (threadIdx.x >> 6);
  const int b = r / F1, j = r - b*F1;
  const int id = ids[b];
  const int i1 = adj[(size_t)id*MAXDEG + P.p1[j]];
  int nid[F2];
  #pragma unroll
  for (int u=0;u<F2;++u) nid[u] = adj[(size_t)i1*MAXDEG + P.p2[u]];
  float4 s = {0.f,0.f,0.f,0.f};
  #pragma unroll
  for (int u=0;u<F2;++u){
    float4 v = feats4[(size_t)nid[u]*D4 + lane];
    s.x+=v.x; s.y+=v.y; s.z+=v.z; s.w+=v.w;
  }
  const float inv = 1.f/F2;
  ushort2 lo = { f2bf(s.x*inv), f2bf(s.y*inv) };
  ushort2 hi = { f2bf(s.z*inv), f2bf(s.w*inv) };
  uint32_t packed[2] = { (uint32_t)lo.x | ((uint32_t)lo.y<<16),
                         (uint32_t)hi.x | ((uint32_t)hi.y<<16) };
  *(uint2*)(M1b + (size_t)r*D + lane*4) = *(uint2*)packed;
}

// ---------------- kernel B: MFMA mega (layer1 + layer2) -------------------
// S rows: 0..24 = feats[ids1], 25 = feats[id], 26..50 = M1, 51 = M0, 52..63 junk
// D = S @ [W1x|W1n]^T  (64x256, MFMA 16x16x32 bf16)
// Z[r<26] = relu(D[r][0:128] | D[26+r][128:256] + b1)
// M2 = colmean(Z[0:25]); z0 = Z[25]; out = [z0@W2x^T+b2x | M2@W2n^T+b2n]
__global__ __launch_bounds__(256, 2) void mega3_k(
    const float4* __restrict__ feats4,
    const int* __restrict__ ids, const int* __restrict__ adj,
    const uint16_t* __restrict__ M1b,
    const float* __restrict__ W1x, const float* __restrict__ b1x,
    const float* __restrict__ W1n, const float* __restrict__ b1n,
    const float* __restrict__ W2x, const float* __restrict__ b2x,
    const float* __restrict__ W2n, const float* __restrict__ b2n,
    float* __restrict__ out, Perms P)
{
  __shared__ uint16_t S[64*SP];        // 33.8 KB bf16, row-major
  __shared__ uint16_t Wt[1024*8];      // 16 KB, fragment-major per k-tile
  __shared__ uint16_t Z[26*ZP];        // 13.5 KB
  __shared__ float    M2s[D];
  __shared__ int      sids[26];

  const int b    = blockIdx.x;
  const int tid  = threadIdx.x;
  const int lane = tid & 63;
  const int w    = tid >> 6;
  const int ln   = lane & 15;
  const int q    = lane >> 4;
  const int id   = ids[b];

  if (tid < F1) sids[tid] = adj[(size_t)id*MAXDEG + P.p1[tid]];
  if (tid == F1) sids[F1] = id;
  __syncthreads();

  // stage self rows (fp32 -> bf16) and M1 rows (bf16 copy)
  for (int idx = tid; idx < 26*D4; idx += 256){
    int r = idx >> 6, c4 = idx & 63;
    float4 v = feats4[(size_t)sids[r]*D4 + c4];
    uint32_t p[2] = { (uint32_t)f2bf(v.x) | ((uint32_t)f2bf(v.y)<<16),
                      (uint32_t)f2bf(v.z) | ((uint32_t)f2bf(v.w)<<16) };
    *(uint2*)(S + r*SP + c4*4) = *(uint2*)p;
  }
  for (int idx = tid; idx < F1*D4; idx += 256){
    int r = idx >> 6, c4 = idx & 63;
    uint2 v = *(const uint2*)(M1b + (size_t)(b*F1 + r)*D + c4*4);
    *(uint2*)(S + (26+r)*SP + c4*4) = v;
  }
  __syncthreads();

  // M0 -> S row 51
  {
    float s = 0.f;
    #pragma unroll
    for (int r=0;r<F1;++r) s += bf2f(S[r*SP + tid]);
    S[51*SP + tid] = f2bf(s * (1.f/F1));
  }
  __syncthreads();

  // ---- layer-1 MFMA GEMM: 8 k-tiles of 32 ----
  f32x4 acc[4][4];
  #pragma unroll
  for (int mt=0;mt<4;++mt)
    #pragma unroll
    for (int nt=0;nt<4;++nt) acc[mt][nt] = (f32x4){0.f,0.f,0.f,0.f};

  for (int kt = 0; kt < 8; ++kt){
    // stage Wt fragment-major: group g=(ntile*4+q)*16+ln holds
    // W[n=ntile*16+ln][k = kt*32 + q*8 .. +8] as 8 bf16 (16 B)
    #pragma unroll
    for (int i=0;i<4;++i){
      int g = tid + i*256;
      int n = ((g >> 6) << 4) | (g & 15);
      int qq = (g >> 4) & 3;
      const float* src = (n < OUTD) ? (W1x + (size_t)n*D)
                                    : (W1n + (size_t)(n-OUTD)*D);
      float4 f0 = *(const float4*)(src + kt*32 + qq*8);
      float4 f1 = *(const float4*)(src + kt*32 + qq*8 + 4);
      uint32_t p[4] = {
        (uint32_t)f2bf(f0.x) | ((uint32_t)f2bf(f0.y)<<16),
        (uint32_t)f2bf(f0.z) | ((uint32_t)f2bf(f0.w)<<16),
        (uint32_t)f2bf(f1.x) | ((uint32_t)f2bf(f1.y)<<16),
        (uint32_t)f2bf(f1.z) | ((uint32_t)f2bf(f1.w)<<16) };
      *(uint4*)(Wt + g*8) = *(uint4*)p;
    }
    __syncthreads();

    s16x8 af[4], bf[4];
    #pragma unroll
    for (int mt=0;mt<4;++mt)
      af[mt] = *(const s16x8*)(S + (mt*16 + ln)*SP + kt*32 + q*8);
    #pragma unroll
    for (int nt=0;nt<4;++nt)
      bf[nt] = *(const s16x8*)(Wt + ((w*4 + nt)*64 + lane)*8);
    #pragma unroll
    for (int mt=0;mt<4;++mt)
      #pragma unroll
      for (int nt=0;nt<4;++nt)
        acc[mt][nt] = __builtin_amdgcn_mfma_f32_16x16x32_bf16(
                        af[mt], bf[nt], acc[mt][nt], 0, 0, 0);
    __syncthreads();
  }

  // ---- epilogue: bias + relu -> Z (bf16) ----
  {
    const bool left = (w < 2);
    float bia[4];
    #pragma unroll
    for (int nt=0;nt<4;++nt){
      int n = w*64 + nt*16 + ln;
      bia[nt] = left ? b1x[n] : b1n[n-OUTD];
    }
    #pragma unroll
    for (int mt=0;mt<4;++mt)
      #pragma unroll
      for (int nt=0;nt<4;++nt){
        int n = w*64 + nt*16 + ln;
        #pragma unroll
        for (int reg=0;reg<4;++reg){
          int m = mt*16 + q*4 + reg;
          float val = fmaxf(acc[mt][nt][reg] + bia[nt], 0.f);
          if (left){
            if (m < 26) Z[m*ZP + n] = f2bf(val);
          } else {
            if (m >= 26 && m < 52) Z[(m-26)*ZP + n] = f2bf(val);
          }
        }
      }
  }
  __syncthreads();

  // M2 = colmean(Z rows 0..24)
  {
    float s = 0.f;
    #pragma unroll
    for (int r=0;r<F1;++r) s += bf2f(Z[r*ZP + tid]);
    M2s[tid] = s * (1.f/F1);
  }
  __syncthreads();

  // ---- layer 2 (fp32 vector, W2 from L2) ----
  {
    const int o = tid;
    const bool l2l = (o < OUTD);
    const float* w2 = l2l ? (W2x + (size_t)o*D) : (W2n + (size_t)(o-OUTD)*D);
    float acc2 = 0.f;
    #pragma unroll 8
    for (int k4=0;k4<D4;++k4){
      float4 wv = *(const float4*)(w2 + k4*4);
      float z0,z1,z2,z3;
      if (l2l){
        z0 = bf2f(Z[25*ZP + k4*4+0]); z1 = bf2f(Z[25*ZP + k4*4+1]);
        z2 = bf2f(Z[25*ZP + k4*4+2]); z3 = bf2f(Z[25*ZP + k4*4+3]);
      } else {
        float4 mv = *(const float4*)(M2s + k4*4);
        z0 = mv.x; z1 = mv.y; z2 = mv.z; z3 = mv.w;
      }
      acc2 += wv.x*z0 + wv.y*z1 + wv.z*z2 + wv.w*z3;
    }
    acc2 += l2l ? b2x[o] : b2n[o-OUTD];
    out[(size_t)b*D + o] = acc2;
  }
}

// ---------------- launch ----------------
extern "C" void kernel_launch(void* const* d_in, const int* in_sizes, int n_in,
                              void* d_out, int out_size, void* d_ws, size_t ws_size,
                              hipStream_t stream){
  const int*   ids   = (const int*)  d_in[0];
  const int*   adj   = (const int*)  d_in[1];
  const float* feats = (const float*)d_in[2];
  const float* W1x   = (const float*)d_in[3];
  const float* b1x   = (const float*)d_in[4];
  const float* W1n   = (const float*)d_in[5];
  const float* b1n   = (const float*)d_in[6];
  const float* W2x   = (const float*)d_in[7];
  const float* b2x   = (const float*)d_in[8];
  const float* W2n   = (const float*)d_in[9];
  const float* b2n   = (const float*)d_in[10];
  float* out = (float*)d_out;

  Perms P;
  compute_perms(P);

  uint16_t* M1b = (uint16_t*)d_ws;   // 25600*256*2 = 13.1 MB

  hipLaunchKernelGGL(mean_k, dim3(BATCH*F1/4), dim3(256), 0, stream,
                     (const float4*)feats, ids, adj, M1b, P);
  hipLaunchKernelGGL(mega3_k, dim3(BATCH), dim3(256), 0, stream,
                     (const float4*)feats, ids, adj, M1b,
                     W1x, b1x, W1n, b1n, W2x, b2x, W2n, b2n, out, P);
}

// Round 5
// 274.292 us; speedup vs baseline: 1.6375x; 1.0328x over previous
//
#include <hip/hip_runtime.h>
#include <stdint.h>
#include <stddef.h>
#include <algorithm>

// GraphSAGE 2-layer, MI355X. RNG: JAX threefry partitionable (verified R1).
// R5: pre-packed weights (bf16 fragment-major W1, transposed fp32 W2),
// barrier-free MFMA k-loop with B-frags straight from L2, 3 blocks/CU.

#define D       256
#define D4      64
#define BATCH   1024
#define F1      25
#define F2      10
#define MAXDEG  128
#define OUTD    128
#define SP      264          // S pitch in bf16 elements (528 B)
#define ZP      260          // Z pitch in bf16 elements

struct Perms { int p1[F1]; int p2[F2]; };

// ---------------- host-side threefry2x32 (JAX-exact, verified R1) ----------
static inline uint32_t rotl32(uint32_t x, int d){ return (x<<d)|(x>>(32-d)); }

static void tf2x32(uint32_t k0, uint32_t k1, uint32_t x0, uint32_t x1,
                   uint32_t* o0, uint32_t* o1){
  uint32_t ks0=k0, ks1=k1, ks2 = k0^k1^0x1BD11BDAu;
  static const int rot[2][4] = {{13,15,26,6},{17,29,16,24}};
  x0 += ks0; x1 += ks1;
  for (int g=0; g<5; ++g){
    const int* r = rot[g&1];
    for (int i=0;i<4;++i){ x0 += x1; x1 = rotl32(x1, r[i]) ^ x0; }
    switch(g){
      case 0: x0 += ks1; x1 += ks2 + 1u; break;
      case 1: x0 += ks2; x1 += ks0 + 2u; break;
      case 2: x0 += ks0; x1 += ks1 + 3u; break;
      case 3: x0 += ks1; x1 += ks2 + 4u; break;
      default:x0 += ks2; x1 += ks0 + 5u; break;
    }
  }
  *o0 = x0; *o1 = x1;
}

static void mkperm(uint32_t ka, uint32_t kb, int n, int* outp){
  uint32_t ska, skb;
  tf2x32(ka, kb, 0u, 1u, &ska, &skb);
  uint32_t bits[MAXDEG];
  int idxs[MAXDEG];
  for (int i=0;i<MAXDEG;++i){
    uint32_t y0,y1; tf2x32(ska,skb, 0u,(uint32_t)i, &y0,&y1);
    bits[i] = y0 ^ y1;
    idxs[i] = i;
  }
  std::stable_sort(idxs, idxs+MAXDEG,
                   [&](int a,int b){ return bits[a] < bits[b]; });
  for (int j=0;j<n;++j) outp[j] = idxs[j];
}

static void compute_perms(Perms& P){
  uint32_t k1a,k1b,k2a,k2b;
  tf2x32(0u,42u, 0u,0u, &k1a,&k1b);
  tf2x32(0u,42u, 0u,1u, &k2a,&k2b);
  mkperm(k1a,k1b, F1, P.p1);
  mkperm(k2a,k2b, F2, P.p2);
}

// ---------------- device helpers ----------------
typedef short s16x8 __attribute__((ext_vector_type(8)));
typedef float f32x4 __attribute__((ext_vector_type(4)));

__device__ __forceinline__ uint16_t f2bf(float f){
  uint32_t u = __float_as_uint(f);
  u += 0x7fffu + ((u >> 16) & 1u);      // RNE
  return (uint16_t)(u >> 16);
}
__device__ __forceinline__ float bf2f(uint16_t h){
  return __uint_as_float(((uint32_t)h) << 16);
}

// ---------------- pack kernels (run every call; tiny) ---------------------
// WB fragment groups: g = (kt*16 + ct)*64 + lane, 8 bf16 each:
//   W[n = ct*16 + (lane&15)][k = kt*32 + (lane>>4)*8 .. +8]
//   n<128 -> W1x, else W1n  (verified mapping, R4)
__global__ __launch_bounds__(256) void pack_w1_k(
    const float* __restrict__ W1x, const float* __restrict__ W1n,
    uint16_t* __restrict__ WB){
  int g = blockIdx.x*256 + threadIdx.x;        // 8192 groups
  int kt = g >> 10, ct = (g >> 6) & 15, lane = g & 63;
  int n = ct*16 + (lane & 15);
  int k = kt*32 + (lane >> 4)*8;
  const float* src = (n < OUTD) ? (W1x + (size_t)n*D + k)
                                : (W1n + (size_t)(n-OUTD)*D + k);
  float4 f0 = *(const float4*)src;
  float4 f1 = *(const float4*)(src + 4);
  uint32_t p[4] = {
    (uint32_t)f2bf(f0.x) | ((uint32_t)f2bf(f0.y)<<16),
    (uint32_t)f2bf(f0.z) | ((uint32_t)f2bf(f0.w)<<16),
    (uint32_t)f2bf(f1.x) | ((uint32_t)f2bf(f1.y)<<16),
    (uint32_t)f2bf(f1.z) | ((uint32_t)f2bf(f1.w)<<16) };
  *(uint4*)(WB + (size_t)g*8) = *(uint4*)p;
}

// W2T[k*256 + o] = (o<128 ? W2x[o][k] : W2n[o-128][k])  (fp32, coalesced use)
__global__ __launch_bounds__(256) void pack_w2_k(
    const float* __restrict__ W2x, const float* __restrict__ W2n,
    float* __restrict__ W2T){
  int idx = blockIdx.x*256 + threadIdx.x;      // 65536
  int k = idx >> 8, o = idx & 255;
  W2T[idx] = (o < OUTD) ? W2x[(size_t)o*D + k] : W2n[(size_t)(o-OUTD)*D + k];
}

// ---------------- kernel A: fused sample + neighbor mean (bf16 out) -------
__global__ __launch_bounds__(256) void mean_k(
    const float4* __restrict__ feats4,
    const int* __restrict__ ids, const int* __restrict__ adj,
    uint16_t* __restrict__ M1b, Perms P)
{
  const int lane = threadIdx.x & 63;
  const int r = blockIdx.x*4 + (threadIdx.x >> 6);
  const int b = r / F1, j = r - b*F1;
  const int id = ids[b];
  const int i1 = adj[(size_t)id*MAXDEG + P.p1[j]];
  int nid[F2];
  #pragma unroll
  for (int u=0;u<F2;++u) nid[u] = adj[(size_t)i1*MAXDEG + P.p2[u]];
  float4 s = {0.f,0.f,0.f,0.f};
  #pragma unroll
  for (int u=0;u<F2;++u){
    float4 v = feats4[(size_t)nid[u]*D4 + lane];
    s.x+=v.x; s.y+=v.y; s.z+=v.z; s.w+=v.w;
  }
  const float inv = 1.f/F2;
  uint32_t p[2] = { (uint32_t)f2bf(s.x*inv) | ((uint32_t)f2bf(s.y*inv)<<16),
                    (uint32_t)f2bf(s.z*inv) | ((uint32_t)f2bf(s.w*inv)<<16) };
  *(uint2*)(M1b + (size_t)r*D + lane*4) = *(uint2*)p;
}

// ---------------- kernel B: MFMA mega (layer1 + layer2) -------------------
// S rows: 0..24 = feats[ids1], 25 = feats[id], 26..50 = M1, 51 = M0, 52..63 = 0
// Dm = S @ [W1x|W1n]^T  (64x256, MFMA 16x16x32, B-frags from global WB)
// Z[r<26] = relu(Dm[r][0:128] | Dm[26+r][128:256] + b1)
// M2 = colmean(Z[0:25]); z0 = Z[25]; out = [z0@W2x^T+b2x | M2@W2n^T+b2n]
__global__ __launch_bounds__(256, 3) void mega4_k(
    const float4* __restrict__ feats4,
    const int* __restrict__ ids, const int* __restrict__ adj,
    const uint16_t* __restrict__ M1b, const uint16_t* __restrict__ WB,
    const float* __restrict__ W2T,
    const float* __restrict__ b1x, const float* __restrict__ b1n,
    const float* __restrict__ b2x, const float* __restrict__ b2n,
    float* __restrict__ out, Perms P)
{
  __shared__ uint16_t S[64*SP];        // 33.8 KB
  __shared__ uint16_t Z[26*ZP];        // 13.2 KB
  __shared__ float    M2s[D];
  __shared__ int      sids[26];

  const int b    = blockIdx.x;
  const int tid  = threadIdx.x;
  const int lane = tid & 63;
  const int w    = tid >> 6;
  const int ln   = lane & 15;
  const int q    = lane >> 4;
  const int id   = ids[b];

  if (tid < F1) sids[tid] = adj[(size_t)id*MAXDEG + P.p1[tid]];
  if (tid == F1) sids[F1] = id;
  __syncthreads();

  // stage S: self rows 0..25 (fp32->bf16), M1 rows 26..50, zero 51..63
  for (int idx = tid; idx < 26*D4; idx += 256){
    int r = idx >> 6, c4 = idx & 63;
    float4 v = feats4[(size_t)sids[r]*D4 + c4];
    uint32_t p[2] = { (uint32_t)f2bf(v.x) | ((uint32_t)f2bf(v.y)<<16),
                      (uint32_t)f2bf(v.z) | ((uint32_t)f2bf(v.w)<<16) };
    *(uint2*)(S + r*SP + c4*4) = *(uint2*)p;
  }
  for (int idx = tid; idx < F1*D4; idx += 256){
    int r = idx >> 6, c4 = idx & 63;
    uint2 v = *(const uint2*)(M1b + (size_t)(b*F1 + r)*D + c4*4);
    *(uint2*)(S + (26+r)*SP + c4*4) = v;
  }
  for (int idx = tid; idx < 13*D4; idx += 256){   // rows 51..63 zeroed
    int r = 51 + (idx >> 6), c4 = idx & 63;
    uint32_t z2[2] = {0u,0u};
    *(uint2*)(S + r*SP + c4*4) = *(uint2*)z2;
  }
  __syncthreads();

  // M0 -> S row 51
  {
    float s = 0.f;
    #pragma unroll
    for (int r=0;r<F1;++r) s += bf2f(S[r*SP + tid]);
    S[51*SP + tid] = f2bf(s * (1.f/F1));
  }
  __syncthreads();

  // ---- layer-1 MFMA GEMM: 8 k-tiles of 32, barrier-free ----
  f32x4 acc[4][4];
  #pragma unroll
  for (int mt=0;mt<4;++mt)
    #pragma unroll
    for (int nt=0;nt<4;++nt) acc[mt][nt] = (f32x4){0.f,0.f,0.f,0.f};

  #pragma unroll 2
  for (int kt = 0; kt < 8; ++kt){
    s16x8 af[4], bf[4];
    #pragma unroll
    for (int mt=0;mt<4;++mt)
      af[mt] = *(const s16x8*)(S + (mt*16 + ln)*SP + kt*32 + q*8);
    #pragma unroll
    for (int nt=0;nt<4;++nt)
      bf[nt] = *(const s16x8*)(WB + (size_t)((kt*16 + w*4 + nt)*64 + lane)*8);
    #pragma unroll
    for (int mt=0;mt<4;++mt)
      #pragma unroll
      for (int nt=0;nt<4;++nt)
        acc[mt][nt] = __builtin_amdgcn_mfma_f32_16x16x32_bf16(
                        af[mt], bf[nt], acc[mt][nt], 0, 0, 0);
  }

  // ---- epilogue: bias + relu -> Z (bf16) ----
  {
    const bool left = (w < 2);
    float bia[4];
    #pragma unroll
    for (int nt=0;nt<4;++nt){
      int n = w*64 + nt*16 + ln;
      bia[nt] = left ? b1x[n] : b1n[n-OUTD];
    }
    #pragma unroll
    for (int mt=0;mt<4;++mt)
      #pragma unroll
      for (int nt=0;nt<4;++nt){
        int n = w*64 + nt*16 + ln;
        #pragma unroll
        for (int reg=0;reg<4;++reg){
          int m = mt*16 + q*4 + reg;
          float val = fmaxf(acc[mt][nt][reg] + bia[nt], 0.f);
          if (left){
            if (m < 26) Z[m*ZP + n] = f2bf(val);
          } else {
            if (m >= 26 && m < 52) Z[(m-26)*ZP + n] = f2bf(val);
          }
        }
      }
  }
  __syncthreads();

  // M2 = colmean(Z rows 0..24)
  {
    float s = 0.f;
    #pragma unroll
    for (int r=0;r<F1;++r) s += bf2f(Z[r*ZP + tid]);
    M2s[tid] = s * (1.f/F1);
  }
  __syncthreads();

  // ---- layer 2: coalesced W2T reads (lane-consecutive o) ----
  {
    const int o = tid;
    const bool l2l = (o < OUTD);
    float acc2 = 0.f;
    #pragma unroll 8
    for (int k=0;k<D;++k){
      float zk = l2l ? bf2f(Z[25*ZP + k]) : M2s[k];
      acc2 += zk * W2T[(size_t)k*D + o];
    }
    acc2 += l2l ? b2x[o] : b2n[o-OUTD];
    out[(size_t)b*D + o] = acc2;
  }
}

// ---------------- launch ----------------
extern "C" void kernel_launch(void* const* d_in, const int* in_sizes, int n_in,
                              void* d_out, int out_size, void* d_ws, size_t ws_size,
                              hipStream_t stream){
  const int*   ids   = (const int*)  d_in[0];
  const int*   adj   = (const int*)  d_in[1];
  const float* feats = (const float*)d_in[2];
  const float* W1x   = (const float*)d_in[3];
  const float* b1x   = (const float*)d_in[4];
  const float* W1n   = (const float*)d_in[5];
  const float* b1n   = (const float*)d_in[6];
  const float* W2x   = (const float*)d_in[7];
  const float* b2x   = (const float*)d_in[8];
  const float* W2n   = (const float*)d_in[9];
  const float* b2n   = (const float*)d_in[10];
  float* out = (float*)d_out;

  Perms P;
  compute_perms(P);

  char* wsb = (char*)d_ws;
  uint16_t* M1b = (uint16_t*)wsb;                    // 13.1 MB
  wsb += (size_t)BATCH*F1*D*sizeof(uint16_t);
  uint16_t* WB  = (uint16_t*)wsb;                    // 131 KB
  wsb += (size_t)8192*8*sizeof(uint16_t);
  float*    W2T = (float*)wsb;                       // 256 KB

  hipLaunchKernelGGL(pack_w1_k, dim3(32), dim3(256), 0, stream, W1x, W1n, WB);
  hipLaunchKernelGGL(pack_w2_k, dim3(256), dim3(256), 0, stream, W2x, W2n, W2T);
  hipLaunchKernelGGL(mean_k, dim3(BATCH*F1/4), dim3(256), 0, stream,
                     (const float4*)feats, ids, adj, M1b, P);
  hipLaunchKernelGGL(mega4_k, dim3(BATCH), dim3(256), 0, stream,
                     (const float4*)feats, ids, adj, M1b, WB, W2T,
                     b1x, b1n, b2x, b2n, out, P);
}

// Round 6
// 233.684 us; speedup vs baseline: 1.9220x; 1.1738x over previous
//
#include <hip/hip_runtime.h>
#include <stdint.h>
#include <stddef.h>
#include <algorithm>

// GraphSAGE 2-layer, MI355X. RNG: JAX threefry partitionable (verified R1).
// R6: LDS union (Z aliases S) -> 4 blocks/CU; MLP-batched staging;
// fp32 z0 capture + vectorized layer-2; merged pack kernel.

#define D       256
#define D4      64
#define BATCH   1024
#define F1      25
#define F2      10
#define MAXDEG  128
#define OUTD    128
#define SP      264          // S pitch in bf16 elements (528 B, 2-way free)
#define ZP      260          // Z pitch in bf16 elements

struct Perms { int p1[F1]; int p2[F2]; };

// ---------------- host-side threefry2x32 (JAX-exact, verified R1) ----------
static inline uint32_t rotl32(uint32_t x, int d){ return (x<<d)|(x>>(32-d)); }

static void tf2x32(uint32_t k0, uint32_t k1, uint32_t x0, uint32_t x1,
                   uint32_t* o0, uint32_t* o1){
  uint32_t ks0=k0, ks1=k1, ks2 = k0^k1^0x1BD11BDAu;
  static const int rot[2][4] = {{13,15,26,6},{17,29,16,24}};
  x0 += ks0; x1 += ks1;
  for (int g=0; g<5; ++g){
    const int* r = rot[g&1];
    for (int i=0;i<4;++i){ x0 += x1; x1 = rotl32(x1, r[i]) ^ x0; }
    switch(g){
      case 0: x0 += ks1; x1 += ks2 + 1u; break;
      case 1: x0 += ks2; x1 += ks0 + 2u; break;
      case 2: x0 += ks0; x1 += ks1 + 3u; break;
      case 3: x0 += ks1; x1 += ks2 + 4u; break;
      default:x0 += ks2; x1 += ks0 + 5u; break;
    }
  }
  *o0 = x0; *o1 = x1;
}

static void mkperm(uint32_t ka, uint32_t kb, int n, int* outp){
  uint32_t ska, skb;
  tf2x32(ka, kb, 0u, 1u, &ska, &skb);
  uint32_t bits[MAXDEG];
  int idxs[MAXDEG];
  for (int i=0;i<MAXDEG;++i){
    uint32_t y0,y1; tf2x32(ska,skb, 0u,(uint32_t)i, &y0,&y1);
    bits[i] = y0 ^ y1;
    idxs[i] = i;
  }
  std::stable_sort(idxs, idxs+MAXDEG,
                   [&](int a,int b){ return bits[a] < bits[b]; });
  for (int j=0;j<n;++j) outp[j] = idxs[j];
}

static void compute_perms(Perms& P){
  uint32_t k1a,k1b,k2a,k2b;
  tf2x32(0u,42u, 0u,0u, &k1a,&k1b);
  tf2x32(0u,42u, 0u,1u, &k2a,&k2b);
  mkperm(k1a,k1b, F1, P.p1);
  mkperm(k2a,k2b, F2, P.p2);
}

// ---------------- device helpers ----------------
typedef short s16x8 __attribute__((ext_vector_type(8)));
typedef float f32x4 __attribute__((ext_vector_type(4)));

__device__ __forceinline__ uint16_t f2bf(float f){
  uint32_t u = __float_as_uint(f);
  u += 0x7fffu + ((u >> 16) & 1u);      // RNE
  return (uint16_t)(u >> 16);
}
__device__ __forceinline__ float bf2f(uint16_t h){
  return __uint_as_float(((uint32_t)h) << 16);
}

// ---------------- merged pack kernel ---------------------------------------
// g < 8192: W1 fragment groups (bf16):  g = (kt*16 + ct)*64 + lane ->
//   W[n=ct*16+(lane&15)][k=kt*32+(lane>>4)*8 ..+8]   n<128 -> W1x else W1n
// g >= 8192: W2T[k*256+o] fp32 transpose.
__global__ __launch_bounds__(256) void pack_k(
    const float* __restrict__ W1x, const float* __restrict__ W1n,
    const float* __restrict__ W2x, const float* __restrict__ W2n,
    uint16_t* __restrict__ WB, float* __restrict__ W2T){
  int g = blockIdx.x*256 + threadIdx.x;
  if (g < 8192){
    int kt = g >> 10, ct = (g >> 6) & 15, lane = g & 63;
    int n = ct*16 + (lane & 15);
    int k = kt*32 + (lane >> 4)*8;
    const float* src = (n < OUTD) ? (W1x + (size_t)n*D + k)
                                  : (W1n + (size_t)(n-OUTD)*D + k);
    float4 f0 = *(const float4*)src;
    float4 f1 = *(const float4*)(src + 4);
    uint32_t p[4] = {
      (uint32_t)f2bf(f0.x) | ((uint32_t)f2bf(f0.y)<<16),
      (uint32_t)f2bf(f0.z) | ((uint32_t)f2bf(f0.w)<<16),
      (uint32_t)f2bf(f1.x) | ((uint32_t)f2bf(f1.y)<<16),
      (uint32_t)f2bf(f1.z) | ((uint32_t)f2bf(f1.w)<<16) };
    *(uint4*)(WB + (size_t)g*8) = *(uint4*)p;
  } else {
    int idx = g - 8192;                       // 65536
    int k = idx >> 8, o = idx & 255;
    W2T[idx] = (o < OUTD) ? W2x[(size_t)o*D + k]
                          : W2n[(size_t)(o-OUTD)*D + k];
  }
}

// ---------------- kernel A: fused sample + neighbor mean (bf16 out) -------
__global__ __launch_bounds__(256) void mean_k(
    const float4* __restrict__ feats4,
    const int* __restrict__ ids, const int* __restrict__ adj,
    uint16_t* __restrict__ M1b, Perms P)
{
  const int lane = threadIdx.x & 63;
  const int r = blockIdx.x*4 + (threadIdx.x >> 6);
  const int b = r / F1, j = r - b*F1;
  const int id = ids[b];
  const int i1 = adj[(size_t)id*MAXDEG + P.p1[j]];
  int nid[F2];
  #pragma unroll
  for (int u=0;u<F2;++u) nid[u] = adj[(size_t)i1*MAXDEG + P.p2[u]];
  float4 s = {0.f,0.f,0.f,0.f};
  #pragma unroll
  for (int u=0;u<F2;++u){
    float4 v = feats4[(size_t)nid[u]*D4 + lane];
    s.x+=v.x; s.y+=v.y; s.z+=v.z; s.w+=v.w;
  }
  const float inv = 1.f/F2;
  uint32_t p[2] = { (uint32_t)f2bf(s.x*inv) | ((uint32_t)f2bf(s.y*inv)<<16),
                    (uint32_t)f2bf(s.z*inv) | ((uint32_t)f2bf(s.w*inv)<<16) };
  *(uint2*)(M1b + (size_t)r*D + lane*4) = *(uint2*)p;
}

// ---------------- kernel B: MFMA mega (layer1 + layer2) -------------------
// S rows: 0..24 = feats[ids1], 25 = feats[id], 26..50 = M1, 51 = M0
// Dm = S @ [W1x|W1n]^T  (64x256, MFMA 16x16x32, B-frags from global WB)
// Z (aliases S) rows r<26 = relu(Dm[r][0:128] | Dm[26+r][128:256] + b1), bf16
// z0 captured fp32 in Z0s; M2 = colmean(Z[0:25]);
// out[b] = [z0@W2x^T + b2x | M2@W2n^T + b2n]  (fp32, W2T coalesced)
__global__ __launch_bounds__(256, 4) void mega5_k(
    const float4* __restrict__ feats4,
    const int* __restrict__ ids, const int* __restrict__ adj,
    const uint16_t* __restrict__ M1b, const uint16_t* __restrict__ WB,
    const float* __restrict__ W2T,
    const float* __restrict__ b1x, const float* __restrict__ b1n,
    const float* __restrict__ b2x, const float* __restrict__ b2n,
    float* __restrict__ out, Perms P)
{
  __shared__ uint16_t S[64*SP];        // 33.8 KB; Z aliases this after GEMM
  __shared__ float    M2s[D];          // 1 KB
  __shared__ float    Z0s[D];          // 1 KB
  __shared__ int      sids[26];
  uint16_t* Z = S;                     // ZP-pitch view, rows 0..25

  const int b    = blockIdx.x;
  const int tid  = threadIdx.x;
  const int lane = tid & 63;
  const int w    = tid >> 6;
  const int ln   = lane & 15;
  const int q    = lane >> 4;
  const int id   = ids[b];

  if (tid < F1) sids[tid] = adj[(size_t)id*MAXDEG + P.p1[tid]];
  if (tid == F1) sids[F1] = id;
  __syncthreads();

  // ---- staging, MLP-batched: all loads issue before any LDS write ----
  float4 va[7];
  uint2  vm[7];
  #pragma unroll
  for (int l=0;l<7;++l){
    int idx = tid + l*256;
    if (idx < 26*D4)
      va[l] = feats4[(size_t)sids[idx>>6]*D4 + (idx&63)];
  }
  #pragma unroll
  for (int l=0;l<7;++l){
    int idx = tid + l*256;
    if (idx < F1*D4)
      vm[l] = *(const uint2*)(M1b + (size_t)(b*F1 + (idx>>6))*D + (idx&63)*4);
  }
  #pragma unroll
  for (int l=0;l<7;++l){
    int idx = tid + l*256;
    if (idx < 26*D4){
      int r = idx>>6, c4 = idx&63;
      uint32_t p[2] = { (uint32_t)f2bf(va[l].x) | ((uint32_t)f2bf(va[l].y)<<16),
                        (uint32_t)f2bf(va[l].z) | ((uint32_t)f2bf(va[l].w)<<16) };
      *(uint2*)(S + r*SP + c4*4) = *(uint2*)p;
    }
  }
  #pragma unroll
  for (int l=0;l<7;++l){
    int idx = tid + l*256;
    if (idx < F1*D4){
      int r = idx>>6, c4 = idx&63;
      *(uint2*)(S + (26+r)*SP + c4*4) = vm[l];
    }
  }
  __syncthreads();

  // M0 -> S row 51 (rows 52..63 left as junk; their Dm rows are discarded)
  {
    float s = 0.f;
    #pragma unroll
    for (int r=0;r<F1;++r) s += bf2f(S[r*SP + tid]);
    S[51*SP + tid] = f2bf(s * (1.f/F1));
  }
  __syncthreads();

  // ---- layer-1 MFMA GEMM: 8 k-tiles of 32, barrier-free ----
  f32x4 acc[4][4];
  #pragma unroll
  for (int mt=0;mt<4;++mt)
    #pragma unroll
    for (int nt=0;nt<4;++nt) acc[mt][nt] = (f32x4){0.f,0.f,0.f,0.f};

  #pragma unroll 2
  for (int kt = 0; kt < 8; ++kt){
    s16x8 af[4], bf[4];
    #pragma unroll
    for (int mt=0;mt<4;++mt)
      af[mt] = *(const s16x8*)(S + (mt*16 + ln)*SP + kt*32 + q*8);
    #pragma unroll
    for (int nt=0;nt<4;++nt)
      bf[nt] = *(const s16x8*)(WB + (size_t)((kt*16 + w*4 + nt)*64 + lane)*8);
    #pragma unroll
    for (int mt=0;mt<4;++mt)
      #pragma unroll
      for (int nt=0;nt<4;++nt)
        acc[mt][nt] = __builtin_amdgcn_mfma_f32_16x16x32_bf16(
                        af[mt], bf[nt], acc[mt][nt], 0, 0, 0);
  }
  __syncthreads();   // all S reads done before Z (alias) writes

  // ---- epilogue: bias + relu -> Z (bf16) + fp32 z0 capture ----
  {
    const bool left = (w < 2);
    float bia[4];
    #pragma unroll
    for (int nt=0;nt<4;++nt){
      int n = w*64 + nt*16 + ln;
      bia[nt] = left ? b1x[n] : b1n[n-OUTD];
    }
    #pragma unroll
    for (int mt=0;mt<4;++mt)
      #pragma unroll
      for (int nt=0;nt<4;++nt){
        int n = w*64 + nt*16 + ln;
        #pragma unroll
        for (int reg=0;reg<4;++reg){
          int m = mt*16 + q*4 + reg;
          float val = fmaxf(acc[mt][nt][reg] + bia[nt], 0.f);
          if (left){
            if (m < 26) Z[m*ZP + n] = f2bf(val);
            if (m == 25) Z0s[n] = val;
          } else {
            if (m >= 26 && m < 52) Z[(m-26)*ZP + n] = f2bf(val);
            if (m == 51) Z0s[n] = val;
          }
        }
      }
  }
  __syncthreads();

  // M2 = colmean(Z rows 0..24)
  {
    float s = 0.f;
    #pragma unroll
    for (int r=0;r<F1;++r) s += bf2f(Z[r*ZP + tid]);
    M2s[tid] = s * (1.f/F1);
  }
  __syncthreads();

  // ---- layer 2: fp32, W2T coalesced, z via float4 LDS broadcasts ----
  {
    const int o = tid;
    const float* zsrc = (o < OUTD) ? Z0s : M2s;   // wave-uniform select
    float acc2 = 0.f;
    #pragma unroll 4
    for (int k4=0;k4<D4;++k4){
      float4 z = *(const float4*)(zsrc + k4*4);
      acc2 += z.x * W2T[(size_t)(k4*4+0)*D + o];
      acc2 += z.y * W2T[(size_t)(k4*4+1)*D + o];
      acc2 += z.z * W2T[(size_t)(k4*4+2)*D + o];
      acc2 += z.w * W2T[(size_t)(k4*4+3)*D + o];
    }
    acc2 += (o < OUTD) ? b2x[o] : b2n[o-OUTD];
    out[(size_t)b*D + o] = acc2;
  }
}

// ---------------- launch ----------------
extern "C" void kernel_launch(void* const* d_in, const int* in_sizes, int n_in,
                              void* d_out, int out_size, void* d_ws, size_t ws_size,
                              hipStream_t stream){
  const int*   ids   = (const int*)  d_in[0];
  const int*   adj   = (const int*)  d_in[1];
  const float* feats = (const float*)d_in[2];
  const float* W1x   = (const float*)d_in[3];
  const float* b1x   = (const float*)d_in[4];
  const float* W1n   = (const float*)d_in[5];
  const float* b1n   = (const float*)d_in[6];
  const float* W2x   = (const float*)d_in[7];
  const float* b2x   = (const float*)d_in[8];
  const float* W2n   = (const float*)d_in[9];
  const float* b2n   = (const float*)d_in[10];
  float* out = (float*)d_out;

  Perms P;
  compute_perms(P);

  char* wsb = (char*)d_ws;
  uint16_t* M1b = (uint16_t*)wsb;                    // 13.1 MB
  wsb += (size_t)BATCH*F1*D*sizeof(uint16_t);
  uint16_t* WB  = (uint16_t*)wsb;                    // 131 KB
  wsb += (size_t)8192*8*sizeof(uint16_t);
  float*    W2T = (float*)wsb;                       // 256 KB

  hipLaunchKernelGGL(pack_k, dim3(288), dim3(256), 0, stream,
                     W1x, W1n, W2x, W2n, WB, W2T);
  hipLaunchKernelGGL(mean_k, dim3(BATCH*F1/4), dim3(256), 0, stream,
                     (const float4*)feats, ids, adj, M1b, P);
  hipLaunchKernelGGL(mega5_k, dim3(BATCH), dim3(256), 0, stream,
                     (const float4*)feats, ids, adj, M1b, WB, W2T,
                     b1x, b1n, b2x, b2n, out, P);
}

// Round 7
// 225.721 us; speedup vs baseline: 1.9898x; 1.0353x over previous
//
#include <hip/hip_runtime.h>
#include <stdint.h>
#include <stddef.h>
#include <algorithm>

// GraphSAGE 2-layer, MI355X. RNG: JAX threefry partitionable (verified R1).
// R7: full fusion — sampling, neighbor means, MFMA layer-1, layer-2 in ONE
// kernel (no M1 round-trip, no serialized dispatch). 4 blocks/CU.

#define D       256
#define D4      64
#define BATCH   1024
#define F1      25
#define F2      10
#define MAXDEG  128
#define OUTD    128
#define SP      264          // S pitch in bf16 elements (528 B, 2-way free)
#define ZP      260          // Z pitch in bf16 elements

struct Perms { int p1[F1]; int p2[F2]; };

// ---------------- host-side threefry2x32 (JAX-exact, verified R1) ----------
static inline uint32_t rotl32(uint32_t x, int d){ return (x<<d)|(x>>(32-d)); }

static void tf2x32(uint32_t k0, uint32_t k1, uint32_t x0, uint32_t x1,
                   uint32_t* o0, uint32_t* o1){
  uint32_t ks0=k0, ks1=k1, ks2 = k0^k1^0x1BD11BDAu;
  static const int rot[2][4] = {{13,15,26,6},{17,29,16,24}};
  x0 += ks0; x1 += ks1;
  for (int g=0; g<5; ++g){
    const int* r = rot[g&1];
    for (int i=0;i<4;++i){ x0 += x1; x1 = rotl32(x1, r[i]) ^ x0; }
    switch(g){
      case 0: x0 += ks1; x1 += ks2 + 1u; break;
      case 1: x0 += ks2; x1 += ks0 + 2u; break;
      case 2: x0 += ks0; x1 += ks1 + 3u; break;
      case 3: x0 += ks1; x1 += ks2 + 4u; break;
      default:x0 += ks2; x1 += ks0 + 5u; break;
    }
  }
  *o0 = x0; *o1 = x1;
}

static void mkperm(uint32_t ka, uint32_t kb, int n, int* outp){
  uint32_t ska, skb;
  tf2x32(ka, kb, 0u, 1u, &ska, &skb);
  uint32_t bits[MAXDEG];
  int idxs[MAXDEG];
  for (int i=0;i<MAXDEG;++i){
    uint32_t y0,y1; tf2x32(ska,skb, 0u,(uint32_t)i, &y0,&y1);
    bits[i] = y0 ^ y1;
    idxs[i] = i;
  }
  std::stable_sort(idxs, idxs+MAXDEG,
                   [&](int a,int b){ return bits[a] < bits[b]; });
  for (int j=0;j<n;++j) outp[j] = idxs[j];
}

static void compute_perms(Perms& P){
  uint32_t k1a,k1b,k2a,k2b;
  tf2x32(0u,42u, 0u,0u, &k1a,&k1b);
  tf2x32(0u,42u, 0u,1u, &k2a,&k2b);
  mkperm(k1a,k1b, F1, P.p1);
  mkperm(k2a,k2b, F2, P.p2);
}

// ---------------- device helpers ----------------
typedef short s16x8 __attribute__((ext_vector_type(8)));
typedef float f32x4 __attribute__((ext_vector_type(4)));

__device__ __forceinline__ uint16_t f2bf(float f){
  uint32_t u = __float_as_uint(f);
  u += 0x7fffu + ((u >> 16) & 1u);      // RNE
  return (uint16_t)(u >> 16);
}
__device__ __forceinline__ float bf2f(uint16_t h){
  return __uint_as_float(((uint32_t)h) << 16);
}

// ---------------- merged pack kernel ---------------------------------------
// g < 8192: W1 bf16 fragment groups: g = (kt*16 + ct)*64 + lane ->
//   W[n=ct*16+(lane&15)][k=kt*32+(lane>>4)*8 ..+8]   n<128 -> W1x else W1n
// g >= 8192: W2T[k*256+o] fp32 transpose.
__global__ __launch_bounds__(256) void pack_k(
    const float* __restrict__ W1x, const float* __restrict__ W1n,
    const float* __restrict__ W2x, const float* __restrict__ W2n,
    uint16_t* __restrict__ WB, float* __restrict__ W2T){
  int g = blockIdx.x*256 + threadIdx.x;
  if (g < 8192){
    int kt = g >> 10, ct = (g >> 6) & 15, lane = g & 63;
    int n = ct*16 + (lane & 15);
    int k = kt*32 + (lane >> 4)*8;
    const float* src = (n < OUTD) ? (W1x + (size_t)n*D + k)
                                  : (W1n + (size_t)(n-OUTD)*D + k);
    float4 f0 = *(const float4*)src;
    float4 f1 = *(const float4*)(src + 4);
    uint32_t p[4] = {
      (uint32_t)f2bf(f0.x) | ((uint32_t)f2bf(f0.y)<<16),
      (uint32_t)f2bf(f0.z) | ((uint32_t)f2bf(f0.w)<<16),
      (uint32_t)f2bf(f1.x) | ((uint32_t)f2bf(f1.y)<<16),
      (uint32_t)f2bf(f1.z) | ((uint32_t)f2bf(f1.w)<<16) };
    *(uint4*)(WB + (size_t)g*8) = *(uint4*)p;
  } else {
    int idx = g - 8192;                       // 65536
    int k = idx >> 8, o = idx & 255;
    W2T[idx] = (o < OUTD) ? W2x[(size_t)o*D + k]
                          : W2n[(size_t)(o-OUTD)*D + k];
  }
}

// ---------------- fused mega kernel ----------------------------------------
// One block per batch element b:
//  sids[0..24]=adj[ids[b],p1], sids[25]=ids[b]; nidx[250]=adj[sids[j],p2[u]]
//  S rows 0..25 = bf16(feats[sids]); rows 26..50 = bf16(mean_u feats[nidx]);
//  row 51 = M0 = colmean(rows 0..24); rows 52..63 junk (discarded outputs).
//  Dm = S @ [W1x|W1n]^T (MFMA 16x16x32, B-frags from global WB, barrier-free)
//  Z (aliases S) r<26 = relu(Dm[r][0:128] | Dm[26+r][128:256] + b1); z0 fp32.
//  M2 = colmean(Z[0:25]); out[b] = [z0@W2x^T+b2x | M2@W2n^T+b2n].
__global__ __launch_bounds__(256, 4) void mega6_k(
    const float4* __restrict__ feats4,
    const int* __restrict__ ids, const int* __restrict__ adj,
    const uint16_t* __restrict__ WB, const float* __restrict__ W2T,
    const float* __restrict__ b1x, const float* __restrict__ b1n,
    const float* __restrict__ b2x, const float* __restrict__ b2n,
    float* __restrict__ out, Perms P)
{
  __shared__ uint16_t S[64*SP];        // 33.8 KB; Z aliases this after GEMM
  __shared__ float    M2s[D];          // 1 KB
  __shared__ float    Z0s[D];          // 1 KB
  __shared__ int      sids[26];
  __shared__ int      nidx[F1*F2];     // 1 KB

  const int b    = blockIdx.x;
  const int tid  = threadIdx.x;
  const int lane = tid & 63;
  const int w    = tid >> 6;
  const int ln   = lane & 15;
  const int q    = lane >> 4;
  const int id   = ids[b];
  uint16_t* Z = S;                     // ZP-pitch view, rows 0..25

  // -- sampling --
  if (tid < F1) sids[tid] = adj[(size_t)id*MAXDEG + P.p1[tid]];
  if (tid == F1) sids[F1] = id;
  __syncthreads();
  if (tid < F1*F2){
    int j = tid / F2, u = tid - (tid/F2)*F2;
    nidx[tid] = adj[(size_t)sids[j]*MAXDEG + P.p2[u]];
  }
  __syncthreads();

  // -- gather phase --
  // self-row loads batched first (complete during the M1 loop)
  float4 va[7];
  #pragma unroll
  for (int l=0;l<7;++l){
    int idx = tid + l*256;
    if (idx < 26*D4)
      va[l] = feats4[(size_t)sids[idx>>6]*D4 + (idx&63)];
  }
  // neighbor means: wave w owns rows j = w, w+4, ...; lane owns float4 col
  #pragma unroll 2
  for (int t=0;t<7;++t){
    int j = w + 4*t;
    if (j < F1){
      const int* np = &nidx[j*F2];
      float4 s = {0.f,0.f,0.f,0.f};
      #pragma unroll
      for (int u=0;u<F2;++u){
        float4 v = feats4[(size_t)np[u]*D4 + lane];
        s.x+=v.x; s.y+=v.y; s.z+=v.z; s.w+=v.w;
      }
      const float inv = 1.f/F2;
      uint32_t p[2] = {
        (uint32_t)f2bf(s.x*inv) | ((uint32_t)f2bf(s.y*inv)<<16),
        (uint32_t)f2bf(s.z*inv) | ((uint32_t)f2bf(s.w*inv)<<16) };
      *(uint2*)(S + (26+j)*SP + lane*4) = *(uint2*)p;
    }
  }
  // store self rows
  #pragma unroll
  for (int l=0;l<7;++l){
    int idx = tid + l*256;
    if (idx < 26*D4){
      int r = idx>>6, c4 = idx&63;
      uint32_t p[2] = { (uint32_t)f2bf(va[l].x) | ((uint32_t)f2bf(va[l].y)<<16),
                        (uint32_t)f2bf(va[l].z) | ((uint32_t)f2bf(va[l].w)<<16) };
      *(uint2*)(S + r*SP + c4*4) = *(uint2*)p;
    }
  }
  __syncthreads();

  // M0 -> S row 51
  {
    float s = 0.f;
    #pragma unroll
    for (int r=0;r<F1;++r) s += bf2f(S[r*SP + tid]);
    S[51*SP + tid] = f2bf(s * (1.f/F1));
  }
  __syncthreads();

  // -- layer-1 MFMA GEMM: 8 k-tiles of 32, barrier-free --
  f32x4 acc[4][4];
  #pragma unroll
  for (int mt=0;mt<4;++mt)
    #pragma unroll
    for (int nt=0;nt<4;++nt) acc[mt][nt] = (f32x4){0.f,0.f,0.f,0.f};

  #pragma unroll 2
  for (int kt = 0; kt < 8; ++kt){
    s16x8 af[4], bf[4];
    #pragma unroll
    for (int mt=0;mt<4;++mt)
      af[mt] = *(const s16x8*)(S + (mt*16 + ln)*SP + kt*32 + q*8);
    #pragma unroll
    for (int nt=0;nt<4;++nt)
      bf[nt] = *(const s16x8*)(WB + (size_t)((kt*16 + w*4 + nt)*64 + lane)*8);
    #pragma unroll
    for (int mt=0;mt<4;++mt)
      #pragma unroll
      for (int nt=0;nt<4;++nt)
        acc[mt][nt] = __builtin_amdgcn_mfma_f32_16x16x32_bf16(
                        af[mt], bf[nt], acc[mt][nt], 0, 0, 0);
  }
  __syncthreads();   // all S reads done before Z (alias) writes

  // -- epilogue: bias + relu -> Z (bf16) + fp32 z0 capture --
  {
    const bool left = (w < 2);
    float bia[4];
    #pragma unroll
    for (int nt=0;nt<4;++nt){
      int n = w*64 + nt*16 + ln;
      bia[nt] = left ? b1x[n] : b1n[n-OUTD];
    }
    #pragma unroll
    for (int mt=0;mt<4;++mt)
      #pragma unroll
      for (int nt=0;nt<4;++nt){
        int n = w*64 + nt*16 + ln;
        #pragma unroll
        for (int reg=0;reg<4;++reg){
          int m = mt*16 + q*4 + reg;
          float val = fmaxf(acc[mt][nt][reg] + bia[nt], 0.f);
          if (left){
            if (m < 26) Z[m*ZP + n] = f2bf(val);
            if (m == 25) Z0s[n] = val;
          } else {
            if (m >= 26 && m < 52) Z[(m-26)*ZP + n] = f2bf(val);
            if (m == 51) Z0s[n] = val;
          }
        }
      }
  }
  __syncthreads();

  // M2 = colmean(Z rows 0..24)
  {
    float s = 0.f;
    #pragma unroll
    for (int r=0;r<F1;++r) s += bf2f(Z[r*ZP + tid]);
    M2s[tid] = s * (1.f/F1);
  }
  __syncthreads();

  // -- layer 2: fp32, W2T coalesced, z via float4 LDS broadcasts --
  {
    const int o = tid;
    const float* zsrc = (o < OUTD) ? Z0s : M2s;   // wave-uniform select
    float acc2 = 0.f;
    #pragma unroll 4
    for (int k4=0;k4<D4;++k4){
      float4 z = *(const float4*)(zsrc + k4*4);
      acc2 += z.x * W2T[(size_t)(k4*4+0)*D + o];
      acc2 += z.y * W2T[(size_t)(k4*4+1)*D + o];
      acc2 += z.z * W2T[(size_t)(k4*4+2)*D + o];
      acc2 += z.w * W2T[(size_t)(k4*4+3)*D + o];
    }
    acc2 += (o < OUTD) ? b2x[o] : b2n[o-OUTD];
    out[(size_t)b*D + o] = acc2;
  }
}

// ---------------- launch ----------------
extern "C" void kernel_launch(void* const* d_in, const int* in_sizes, int n_in,
                              void* d_out, int out_size, void* d_ws, size_t ws_size,
                              hipStream_t stream){
  const int*   ids   = (const int*)  d_in[0];
  const int*   adj   = (const int*)  d_in[1];
  const float* feats = (const float*)d_in[2];
  const float* W1x   = (const float*)d_in[3];
  const float* b1x   = (const float*)d_in[4];
  const float* W1n   = (const float*)d_in[5];
  const float* b1n   = (const float*)d_in[6];
  const float* W2x   = (const float*)d_in[7];
  const float* b2x   = (const float*)d_in[8];
  const float* W2n   = (const float*)d_in[9];
  const float* b2n   = (const float*)d_in[10];
  float* out = (float*)d_out;

  Perms P;
  compute_perms(P);

  char* wsb = (char*)d_ws;
  uint16_t* WB  = (uint16_t*)wsb;                    // 131 KB
  wsb += (size_t)8192*8*sizeof(uint16_t);
  float*    W2T = (float*)wsb;                       // 256 KB

  hipLaunchKernelGGL(pack_k, dim3(288), dim3(256), 0, stream,
                     W1x, W1n, W2x, W2n, WB, W2T);
  hipLaunchKernelGGL(mega6_k, dim3(BATCH), dim3(256), 0, stream,
                     (const float4*)feats, ids, adj, WB, W2T,
                     b1x, b1n, b2x, b2n, out, P);
}